// Round 3
// baseline (1182.075 us; speedup 1.0000x reference)
//
#include <hip/hip_runtime.h>
#include <math.h>

typedef __attribute__((ext_vector_type(8))) unsigned short ushort8;
typedef __attribute__((ext_vector_type(8))) __bf16 bf16x8;
typedef __attribute__((ext_vector_type(4))) float floatx4;

constexpr int IMGW = 384;
constexpr int NPIX = IMGW * IMGW;

__device__ __forceinline__ unsigned short f2bf(float f) {
  union { float f; unsigned u; } v; v.f = f;
  unsigned u = v.u;
  return (unsigned short)((u + 0x7fffu + ((u >> 16) & 1u)) >> 16);
}
__device__ __forceinline__ float bf2f(unsigned short h) {
  union { unsigned u; float f; } v; v.u = ((unsigned)h) << 16; return v.f;
}
__device__ __forceinline__ floatx4 mfma16(bf16x8 a, bf16x8 b, floatx4 c) {
  return __builtin_amdgcn_mfma_f32_16x16x32_bf16(a, b, c, 0, 0, 0);
}
__device__ __forceinline__ bf16x8 lds_frag(const unsigned short* p) {
  return *reinterpret_cast<const bf16x8*>(p);
}

// ---------------- weight prep ----------------
__global__ void prep_mlp(const float* __restrict__ w1, const float* __restrict__ w2,
                         const float* __restrict__ w3,
                         unsigned short* __restrict__ w1t, unsigned short* __restrict__ w2t,
                         unsigned short* __restrict__ w3t) {
  int i = blockIdx.x * 256 + threadIdx.x;
  if (i < 8192) {
    int n = i >> 6, k = i & 63;
    w1t[i] = f2bf(k < 63 ? w1[k * 128 + n] : 0.0f);
  } else if (i < 8192 + 16384) {
    int j = i - 8192; int n = j >> 7, k = j & 127;
    w2t[j] = f2bf(w2[k * 128 + n]);
  } else if (i < 8192 + 16384 + 4096) {
    int j = i - 24576; int n = j >> 7, k = j & 127;
    w3t[j] = f2bf(w3[k * 32 + n]);
  }
}

// OIHW fp32 -> swizzled B: dst[ (ks*4+g)*NT + nt ][ lane ][ 8 ]
// so one wave's (ks,nt) fragment is a contiguous, coalesced 1KiB load.
// lane = q*16+m; row co = (g*NT+nt)*16 + m; col k = ks*32 + q*8 + j.
__global__ void prep_convB(const float* __restrict__ w, unsigned short* __restrict__ wt,
                           int total, int CIN, int NT) {
  int i = blockIdx.x * 256 + threadIdx.x;
  if (i >= total) return;
  int j = i & 7, lane = (i >> 3) & 63;
  int rest = i >> 9;
  int nt = rest % NT; rest /= NT;
  int g = rest & 3; int ks = rest >> 2;
  int q = lane >> 4, m = lane & 15;
  int co = (g * NT + nt) * 16 + m;
  int k = ks * 32 + q * 8 + j;
  int nb = k / CIN, ci = k - nb * CIN;
  wt[i] = f2bf(w[(co * CIN + ci) * 9 + nb]);
}

// ---------------- per-pixel dir-PE contribution: dconG[pixel][32] ----------------
__global__ __launch_bounds__(256) void dcon_kernel(
    const float* __restrict__ ray, const float* __restrict__ w3,
    const float* __restrict__ b3, float* __restrict__ dconG) {
  int gid = blockIdx.x * 256 + threadIdx.x;
  int pixel = gid >> 5, c = gid & 31;
  const float* r = ray + (size_t)pixel * 7;
  float d0 = r[3], d1 = r[4], d2 = r[5];
  float acc = b3[c];
  acc += d0 * w3[128 * 32 + c] + d1 * w3[129 * 32 + c] + d2 * w3[130 * 32 + c];
  float dv[3] = { d0, d1, d2 };
  #pragma unroll
  for (int cc = 0; cc < 3; ++cc) {
    float fs = 1.0f;
    #pragma unroll
    for (int f = 0; f < 4; ++f) {
      float s, co;
      __sincosf(dv[cc] * fs, &s, &co);
      acc += s * w3[(131 + cc * 4 + f) * 32 + c];
      acc += co * w3[(143 + cc * 4 + f) * 32 + c];
      fs *= 2.0f;
    }
  }
  dconG[gid] = acc;
}

// ---------------- fused per-sample MLP ----------------
// 128 threads (2 waves), 64 samples/block. Each wave touches only its own 32
// rows of X/H: H1 aliases X, H2 overwrites H1 in place.
// LDS: 64*136*2 + 2048 + 256 = 19712 B -> 8 blocks/CU.
__global__ __launch_bounds__(128, 4) void mlp_kernel(
    const float* __restrict__ zbufs, const float* __restrict__ ray,
    const int* __restrict__ isTrain,
    const float* __restrict__ b1, const float* __restrict__ b2,
    const unsigned short* __restrict__ w1t, const unsigned short* __restrict__ w2t,
    const unsigned short* __restrict__ w3t, const float* __restrict__ dconG,
    unsigned short* __restrict__ rdmp) {
  __shared__ __align__(16) unsigned short XH[64 * 136];
  __shared__ float dcon[16 * 32];
  __shared__ float maskv[64];

  const int tid = threadIdx.x;
  const float thresh = (isTrain[0] != 0) ? 0.2f : 0.0f;

  // phase 0: PE spread across all 128 threads (2 threads per sample)
  {
    int s = tid >> 1, h = tid & 1;
    int sg = blockIdx.x * 64 + s;
    int pixel = sg >> 2;
    float z = zbufs[sg];
    const float* r = ray + (size_t)pixel * 7;
    float t = z / r[6];
    float xv[3] = { r[0] + r[3] * t, r[1] + r[4] * t, r[2] + r[5] * t };
    unsigned short* Xr = XH + s * 72;
    if (h == 0) {
      maskv[s] = (z > thresh) ? 1.0f : 0.0f;
      Xr[0] = f2bf(xv[0]); Xr[1] = f2bf(xv[1]); Xr[2] = f2bf(xv[2]);
      Xr[63] = 0;
    }
    float fb = h ? 32.0f : 1.0f;
    int fo = h * 5;
    #pragma unroll
    for (int c = 0; c < 3; ++c)
      #pragma unroll
      for (int fi = 0; fi < 5; ++fi) {
        float s_, c_;
        __sincosf(xv[c] * (fb * (float)(1 << fi)), &s_, &c_);
        Xr[3 + c * 10 + fo + fi]  = f2bf(s_);
        Xr[33 + c * 10 + fo + fi] = f2bf(c_);
      }
  }
  {
    const float* src = dconG + (size_t)blockIdx.x * 512;
    #pragma unroll
    for (int j = 0; j < 4; ++j) dcon[tid + 128 * j] = src[tid + 128 * j];
  }
  __syncthreads();

  const int wave = tid >> 6, lane = tid & 63, q = lane >> 4, m = lane & 15;
  const int row0 = wave * 32;

  // ---- layer 1: X(64x64) @ w1t -> H1 (relu), H1 aliases X ----
  {
    floatx4 acc[2][8] = {};
    #pragma unroll
    for (int ks = 0; ks < 2; ++ks) {
      bf16x8 a[2];
      #pragma unroll
      for (int mt = 0; mt < 2; ++mt)
        a[mt] = lds_frag(XH + (row0 + mt * 16 + m) * 72 + ks * 32 + q * 8);
      #pragma unroll
      for (int nt = 0; nt < 8; ++nt) {
        bf16x8 b = *reinterpret_cast<const bf16x8*>(w1t + (nt * 16 + m) * 64 + ks * 32 + q * 8);
        #pragma unroll
        for (int mt = 0; mt < 2; ++mt)
          acc[mt][nt] = mfma16(a[mt], b, acc[mt][nt]);
      }
    }
    __syncthreads();
    #pragma unroll
    for (int mt = 0; mt < 2; ++mt)
      #pragma unroll
      for (int nt = 0; nt < 8; ++nt) {
        int col = nt * 16 + m;
        float bb = b1[col];
        #pragma unroll
        for (int r = 0; r < 4; ++r) {
          int row = row0 + mt * 16 + q * 4 + r;
          XH[row * 136 + col] = f2bf(fmaxf(acc[mt][nt][r] + bb, 0.0f));
        }
      }
  }

  // ---- layer 2: H1 @ w2t -> H2 (relu), in place ----
  {
    floatx4 acc[2][8] = {};
    #pragma unroll
    for (int ks = 0; ks < 4; ++ks) {
      bf16x8 a[2];
      #pragma unroll
      for (int mt = 0; mt < 2; ++mt)
        a[mt] = lds_frag(XH + (row0 + mt * 16 + m) * 136 + ks * 32 + q * 8);
      #pragma unroll
      for (int nt = 0; nt < 8; ++nt) {
        bf16x8 b = *reinterpret_cast<const bf16x8*>(w2t + (nt * 16 + m) * 128 + ks * 32 + q * 8);
        #pragma unroll
        for (int mt = 0; mt < 2; ++mt)
          acc[mt][nt] = mfma16(a[mt], b, acc[mt][nt]);
      }
    }
    #pragma unroll
    for (int mt = 0; mt < 2; ++mt)
      #pragma unroll
      for (int nt = 0; nt < 8; ++nt) {
        int col = nt * 16 + m;
        float bb = b2[col];
        #pragma unroll
        for (int r = 0; r < 4; ++r) {
          int row = row0 + mt * 16 + q * 4 + r;
          XH[row * 136 + col] = f2bf(fmaxf(acc[mt][nt][r] + bb, 0.0f));
        }
      }
  }

  // ---- layer 3: H2 @ w3t (+dcon), mask, scatter NHWC ----
  {
    floatx4 acc[2][2];
    #pragma unroll
    for (int mt = 0; mt < 2; ++mt)
      #pragma unroll
      for (int nt = 0; nt < 2; ++nt)
        #pragma unroll
        for (int r = 0; r < 4; ++r) {
          int row = row0 + mt * 16 + q * 4 + r;
          acc[mt][nt][r] = dcon[(row >> 2) * 32 + nt * 16 + m];
        }
    #pragma unroll
    for (int ks = 0; ks < 4; ++ks) {
      bf16x8 a[2];
      #pragma unroll
      for (int mt = 0; mt < 2; ++mt)
        a[mt] = lds_frag(XH + (row0 + mt * 16 + m) * 136 + ks * 32 + q * 8);
      #pragma unroll
      for (int nt = 0; nt < 2; ++nt) {
        bf16x8 b = *reinterpret_cast<const bf16x8*>(w3t + (nt * 16 + m) * 128 + ks * 32 + q * 8);
        #pragma unroll
        for (int mt = 0; mt < 2; ++mt)
          acc[mt][nt] = mfma16(a[mt], b, acc[mt][nt]);
      }
    }
    #pragma unroll
    for (int mt = 0; mt < 2; ++mt)
      #pragma unroll
      for (int nt = 0; nt < 2; ++nt)
        #pragma unroll
        for (int r = 0; r < 4; ++r) {
          int row = row0 + mt * 16 + q * 4 + r;
          int sg = blockIdx.x * 64 + row;
          int pixel = sg >> 2, p = sg & 3;
          float v = acc[mt][nt][r] * maskv[row];
          rdmp[(size_t)pixel * 128 + p * 32 + nt * 16 + m] = f2bf(v);
        }
  }
}

// ---------------- NHWC 3x3 conv via MFMA ----------------
// 256 thr, output tile 16x8 pixels. Each wave owns a DISJOINT cout quarter
// (NT=COUT/64 n-tiles) and ALL 8 rows (MT=8): per k-step, NT coalesced 1KiB
// B-loads feed 8*NT MFMAs (B amortized 8x), 8 LDS A-reads feed NT MFMAs each.
// Fully-unrolled K-loop for compiler software pipelining.
// MODE 0: relu -> bf16. MODE 1: sigmoid(acc)*rdmp -> bf16.
template<int CIN, int COUT, int MODE>
__global__ __launch_bounds__(256, (CIN == 128) ? 3 : 4) void conv3x3(
    const unsigned short* __restrict__ in, const unsigned short* __restrict__ wt,
    const float* __restrict__ bias, const unsigned short* __restrict__ rdmp,
    unsigned short* __restrict__ out) {
  constexpr int CP  = CIN + 8;
  constexpr int CH8 = CIN / 8;
  constexpr int KC  = CIN / 32;
  constexpr int NT  = COUT / 64;
  __shared__ __align__(16) unsigned short lds_in[10 * 18 * CP];

  const int tid = threadIdx.x;
  const int x0 = blockIdx.x * 16, y0 = blockIdx.y * 8;

  for (int i = tid; i < 180 * CH8; i += 256) {
    int pix = i / CH8, part = i - pix * CH8;
    int xx = pix % 18, yy = pix / 18;
    int gx = x0 - 1 + xx, gy = y0 - 1 + yy;
    ushort8 v = {0, 0, 0, 0, 0, 0, 0, 0};
    if (gx >= 0 && gx < IMGW && gy >= 0 && gy < IMGW)
      v = *reinterpret_cast<const ushort8*>(in + ((size_t)(gy * IMGW + gx)) * CIN + part * 8);
    *reinterpret_cast<ushort8*>(&lds_in[pix * CP + part * 8]) = v;
  }
  __syncthreads();

  const int wave = tid >> 6, lane = tid & 63, q = lane >> 4, m = lane & 15;
  floatx4 acc[8][NT] = {};

  #pragma unroll
  for (int nb = 0; nb < 9; ++nb) {
    int dy = nb / 3, dx = nb - dy * 3;
    #pragma unroll
    for (int kc = 0; kc < KC; ++kc) {
      int ks = nb * KC + kc;
      int cb = kc * 32 + q * 8;
      bf16x8 a[8];
      #pragma unroll
      for (int mt = 0; mt < 8; ++mt)
        a[mt] = lds_frag(&lds_in[((mt + dy) * 18 + (m + dx)) * CP + cb]);
      #pragma unroll
      for (int nt = 0; nt < NT; ++nt) {
        bf16x8 b = *reinterpret_cast<const bf16x8*>(
            wt + ((((size_t)(ks * 4 + wave)) * NT + nt) << 9) + lane * 8);
        #pragma unroll
        for (int mt = 0; mt < 8; ++mt)
          acc[mt][nt] = mfma16(a[mt], b, acc[mt][nt]);
      }
    }
  }

  const int co0 = wave * (COUT / 4);
  #pragma unroll
  for (int mt = 0; mt < 8; ++mt) {
    int y = y0 + mt;
    #pragma unroll
    for (int nt = 0; nt < NT; ++nt) {
      int co = co0 + nt * 16 + m;
      float bb = bias[co];
      #pragma unroll
      for (int r = 0; r < 4; ++r) {
        int pixel = y * IMGW + x0 + q * 4 + r;
        float v = acc[mt][nt][r] + bb;
        if (MODE == 0) {
          v = fmaxf(v, 0.0f);
        } else {
          v = 1.0f / (1.0f + __expf(-v));
          v *= bf2f(rdmp[(size_t)pixel * 128 + co]);
        }
        out[(size_t)pixel * COUT + co] = f2bf(v);
      }
    }
  }
}

// ---------------- final 64->3 conv + sigmoid, fp32 NHWC out ----------------
__global__ __launch_bounds__(256) void uconv3_kernel(
    const unsigned short* __restrict__ u2, const float* __restrict__ w,
    const float* __restrict__ b, float* __restrict__ out) {
  __shared__ float wl[1728];   // [nb][ci][c]
  for (int i = threadIdx.x; i < 1728; i += 256) {
    int c = i % 3; int t = i / 3; int ci = t & 63; int nb = t >> 6;
    wl[i] = w[(c * 64 + ci) * 9 + nb];
  }
  __syncthreads();
  int pixel = blockIdx.x * 256 + threadIdx.x;
  int py = pixel / IMGW, px = pixel - py * IMGW;
  float a0 = b[0], a1 = b[1], a2 = b[2];
  for (int nb = 0; nb < 9; ++nb) {
    int gy = py + nb / 3 - 1, gx = px + nb % 3 - 1;
    if (gx < 0 || gx >= IMGW || gy < 0 || gy >= IMGW) continue;
    const unsigned short* src = u2 + (size_t)(gy * IMGW + gx) * 64;
    const float* wp = wl + nb * 192;
    #pragma unroll
    for (int cc = 0; cc < 8; ++cc) {
      ushort8 v = *reinterpret_cast<const ushort8*>(src + cc * 8);
      #pragma unroll
      for (int j = 0; j < 8; ++j) {
        float uv = bf2f(v[j]);
        const float* w3p = wp + (cc * 8 + j) * 3;
        a0 += uv * w3p[0]; a1 += uv * w3p[1]; a2 += uv * w3p[2];
      }
    }
  }
  float* o = out + (size_t)pixel * 3;
  o[0] = 1.0f / (1.0f + __expf(-a0));
  o[1] = 1.0f / (1.0f + __expf(-a1));
  o[2] = 1.0f / (1.0f + __expf(-a2));
}

extern "C" void kernel_launch(void* const* d_in, const int* in_sizes, int n_in,
                              void* d_out, int out_size, void* d_ws, size_t ws_size,
                              hipStream_t stream) {
  (void)in_sizes; (void)n_in; (void)out_size; (void)ws_size;
  const float* zbufs = (const float*)d_in[0];
  const float* ray   = (const float*)d_in[1];
  const int* isTrain = (const int*)d_in[4];
  const float* w1 = (const float*)d_in[6];
  const float* b1 = (const float*)d_in[7];
  const float* w2 = (const float*)d_in[8];
  const float* b2 = (const float*)d_in[9];
  const float* w3 = (const float*)d_in[10];
  const float* b3 = (const float*)d_in[11];
  const float* mpn_w1 = (const float*)d_in[12];
  const float* mpn_b1 = (const float*)d_in[13];
  const float* mpn_w2 = (const float*)d_in[14];
  const float* mpn_b2 = (const float*)d_in[15];
  const float* uw1 = (const float*)d_in[16];
  const float* ub1 = (const float*)d_in[17];
  const float* uw2 = (const float*)d_in[18];
  const float* ub2 = (const float*)d_in[19];
  const float* uw3 = (const float*)d_in[20];
  const float* ub3 = (const float*)d_in[21];
  float* out = (float*)d_out;

  unsigned char* ws = (unsigned char*)d_ws;
  size_t off = 0;
  auto alloc = [&](size_t bytes) -> void* {
    void* p = ws + off; off = (off + bytes + 255) & ~(size_t)255; return p;
  };
  unsigned short* w1t  = (unsigned short*)alloc(8192 * 2);
  unsigned short* w2t  = (unsigned short*)alloc(16384 * 2);
  unsigned short* w3t  = (unsigned short*)alloc(4096 * 2);
  unsigned short* cw1  = (unsigned short*)alloc((size_t)128 * 1152 * 2);
  unsigned short* cw2  = (unsigned short*)alloc((size_t)128 * 1152 * 2);
  unsigned short* cu1  = (unsigned short*)alloc((size_t)64 * 1152 * 2);
  unsigned short* cu2  = (unsigned short*)alloc((size_t)64 * 576 * 2);
  unsigned short* rdmp = (unsigned short*)alloc((size_t)NPIX * 128 * 2);
  unsigned short* t1   = (unsigned short*)alloc((size_t)NPIX * 128 * 2);
  unsigned short* fuse = (unsigned short*)alloc((size_t)NPIX * 128 * 2);
  unsigned short* u1 = t1;            // t1 dead after conv2
  unsigned short* u2 = rdmp;          // rdmp dead after conv2 (fuse epilogue)
  float* dconG = (float*)fuse;        // dconG dead before conv2 writes fuse

  prep_mlp<<<112, 256, 0, stream>>>(w1, w2, w3, w1t, w2t, w3t);
  prep_convB<<<576, 256, 0, stream>>>(mpn_w1, cw1, 128 * 1152, 128, 2);
  prep_convB<<<576, 256, 0, stream>>>(mpn_w2, cw2, 128 * 1152, 128, 2);
  prep_convB<<<288, 256, 0, stream>>>(uw1, cu1, 64 * 1152, 128, 1);
  prep_convB<<<144, 256, 0, stream>>>(uw2, cu2, 64 * 576, 64, 1);

  dcon_kernel<<<NPIX * 32 / 256, 256, 0, stream>>>(ray, w3, b3, dconG);
  mlp_kernel<<<NPIX * 4 / 64, 128, 0, stream>>>(zbufs, ray, isTrain, b1, b2,
                                                w1t, w2t, w3t, dconG, rdmp);

  dim3 cgrid(IMGW / 16, IMGW / 8);
  conv3x3<128, 128, 0><<<cgrid, 256, 0, stream>>>(rdmp, cw1, mpn_b1, nullptr, t1);
  conv3x3<128, 128, 1><<<cgrid, 256, 0, stream>>>(t1, cw2, mpn_b2, rdmp, fuse);
  conv3x3<128, 64, 0><<<cgrid, 256, 0, stream>>>(fuse, cu1, ub1, nullptr, u1);
  conv3x3<64, 64, 0><<<cgrid, 256, 0, stream>>>(u1, cu2, ub2, nullptr, u2);
  uconv3_kernel<<<NPIX / 256, 256, 0, stream>>>(u2, uw3, ub3, out);
}

// Round 4
// 442.730 us; speedup vs baseline: 2.6700x; 2.6700x over previous
//
#include <hip/hip_runtime.h>
#include <math.h>

typedef __attribute__((ext_vector_type(8))) unsigned short ushort8;
typedef __attribute__((ext_vector_type(8))) __bf16 bf16x8;
typedef __attribute__((ext_vector_type(4))) float floatx4;

constexpr int IMGW = 384;
constexpr int NPIX = IMGW * IMGW;

__device__ __forceinline__ unsigned short f2bf(float f) {
  union { float f; unsigned u; } v; v.f = f;
  unsigned u = v.u;
  return (unsigned short)((u + 0x7fffu + ((u >> 16) & 1u)) >> 16);
}
__device__ __forceinline__ float bf2f(unsigned short h) {
  union { unsigned u; float f; } v; v.u = ((unsigned)h) << 16; return v.f;
}
__device__ __forceinline__ floatx4 mfma16(bf16x8 a, bf16x8 b, floatx4 c) {
  return __builtin_amdgcn_mfma_f32_16x16x32_bf16(a, b, c, 0, 0, 0);
}
__device__ __forceinline__ bf16x8 lds_frag(const unsigned short* p) {
  return *reinterpret_cast<const bf16x8*>(p);
}

// ---------------- weight prep ----------------
__global__ void prep_mlp(const float* __restrict__ w1, const float* __restrict__ w2,
                         const float* __restrict__ w3,
                         unsigned short* __restrict__ w1t, unsigned short* __restrict__ w2t,
                         unsigned short* __restrict__ w3t) {
  int i = blockIdx.x * 256 + threadIdx.x;
  if (i < 8192) {
    int n = i >> 6, k = i & 63;
    w1t[i] = f2bf(k < 63 ? w1[k * 128 + n] : 0.0f);
  } else if (i < 8192 + 16384) {
    int j = i - 8192; int n = j >> 7, k = j & 127;
    w2t[j] = f2bf(w2[k * 128 + n]);
  } else if (i < 8192 + 16384 + 4096) {
    int j = i - 24576; int n = j >> 7, k = j & 127;
    w3t[j] = f2bf(w3[k * 32 + n]);
  }
}

// OIHW fp32 -> swizzled B: flat idx = ((ks*G + g)*NT + nt)*512 + lane*8 + j
// One wave's (ks,nt) fragment = contiguous coalesced 1 KiB.
// co = (g*NT+nt)*16 + m;  k = ks*32 + q*8 + j;  lane = q*16+m.
__global__ void prep_convB(const float* __restrict__ w, unsigned short* __restrict__ wt,
                           int total, int CIN, int G, int NT) {
  int i = blockIdx.x * 256 + threadIdx.x;
  if (i >= total) return;
  int j = i & 7, lane = (i >> 3) & 63;
  int rest = i >> 9;
  int nt = rest % NT; int rest2 = rest / NT;
  int g = rest2 % G;  int ks = rest2 / G;
  int q = lane >> 4, m = lane & 15;
  int co = (g * NT + nt) * 16 + m;
  int k = ks * 32 + q * 8 + j;
  int nb = k / CIN, ci = k - nb * CIN;
  wt[i] = f2bf(w[(co * CIN + ci) * 9 + nb]);
}

// ---------------- per-pixel dir-PE contribution: dconG[pixel][32] ----------------
__global__ __launch_bounds__(256) void dcon_kernel(
    const float* __restrict__ ray, const float* __restrict__ w3,
    const float* __restrict__ b3, float* __restrict__ dconG) {
  int gid = blockIdx.x * 256 + threadIdx.x;
  int pixel = gid >> 5, c = gid & 31;
  const float* r = ray + (size_t)pixel * 7;
  float d0 = r[3], d1 = r[4], d2 = r[5];
  float acc = b3[c];
  acc += d0 * w3[128 * 32 + c] + d1 * w3[129 * 32 + c] + d2 * w3[130 * 32 + c];
  float dv[3] = { d0, d1, d2 };
  #pragma unroll
  for (int cc = 0; cc < 3; ++cc) {
    float fs = 1.0f;
    #pragma unroll
    for (int f = 0; f < 4; ++f) {
      float s, co;
      __sincosf(dv[cc] * fs, &s, &co);
      acc += s * w3[(131 + cc * 4 + f) * 32 + c];
      acc += co * w3[(143 + cc * 4 + f) * 32 + c];
      fs *= 2.0f;
    }
  }
  dconG[gid] = acc;
}

// ---------------- fused per-sample MLP ----------------
__global__ __launch_bounds__(128, 4) void mlp_kernel(
    const float* __restrict__ zbufs, const float* __restrict__ ray,
    const int* __restrict__ isTrain,
    const float* __restrict__ b1, const float* __restrict__ b2,
    const unsigned short* __restrict__ w1t, const unsigned short* __restrict__ w2t,
    const unsigned short* __restrict__ w3t, const float* __restrict__ dconG,
    unsigned short* __restrict__ rdmp) {
  __shared__ __align__(16) unsigned short XH[64 * 136];
  __shared__ float dcon[16 * 32];
  __shared__ float maskv[64];

  const int tid = threadIdx.x;
  const float thresh = (isTrain[0] != 0) ? 0.2f : 0.0f;

  {
    int s = tid >> 1, h = tid & 1;
    int sg = blockIdx.x * 64 + s;
    int pixel = sg >> 2;
    float z = zbufs[sg];
    const float* r = ray + (size_t)pixel * 7;
    float t = z / r[6];
    float xv[3] = { r[0] + r[3] * t, r[1] + r[4] * t, r[2] + r[5] * t };
    unsigned short* Xr = XH + s * 72;
    if (h == 0) {
      maskv[s] = (z > thresh) ? 1.0f : 0.0f;
      Xr[0] = f2bf(xv[0]); Xr[1] = f2bf(xv[1]); Xr[2] = f2bf(xv[2]);
      Xr[63] = 0;
    }
    float fb = h ? 32.0f : 1.0f;
    int fo = h * 5;
    #pragma unroll
    for (int c = 0; c < 3; ++c)
      #pragma unroll
      for (int fi = 0; fi < 5; ++fi) {
        float s_, c_;
        __sincosf(xv[c] * (fb * (float)(1 << fi)), &s_, &c_);
        Xr[3 + c * 10 + fo + fi]  = f2bf(s_);
        Xr[33 + c * 10 + fo + fi] = f2bf(c_);
      }
  }
  {
    const float* src = dconG + (size_t)blockIdx.x * 512;
    #pragma unroll
    for (int j = 0; j < 4; ++j) dcon[tid + 128 * j] = src[tid + 128 * j];
  }
  __syncthreads();

  const int wave = tid >> 6, lane = tid & 63, q = lane >> 4, m = lane & 15;
  const int row0 = wave * 32;

  // layer 1: X(64x64) @ w1t -> H1 (relu), H1 aliases X
  {
    floatx4 acc[2][8] = {};
    #pragma unroll
    for (int ks = 0; ks < 2; ++ks) {
      bf16x8 a[2];
      #pragma unroll
      for (int mt = 0; mt < 2; ++mt)
        a[mt] = lds_frag(XH + (row0 + mt * 16 + m) * 72 + ks * 32 + q * 8);
      #pragma unroll
      for (int nt = 0; nt < 8; ++nt) {
        bf16x8 b = *reinterpret_cast<const bf16x8*>(w1t + (nt * 16 + m) * 64 + ks * 32 + q * 8);
        #pragma unroll
        for (int mt = 0; mt < 2; ++mt)
          acc[mt][nt] = mfma16(a[mt], b, acc[mt][nt]);
      }
    }
    __syncthreads();
    #pragma unroll
    for (int mt = 0; mt < 2; ++mt)
      #pragma unroll
      for (int nt = 0; nt < 8; ++nt) {
        int col = nt * 16 + m;
        float bb = b1[col];
        #pragma unroll
        for (int r = 0; r < 4; ++r) {
          int row = row0 + mt * 16 + q * 4 + r;
          XH[row * 136 + col] = f2bf(fmaxf(acc[mt][nt][r] + bb, 0.0f));
        }
      }
  }

  // layer 2: H1 @ w2t -> H2 (relu), in place
  {
    floatx4 acc[2][8] = {};
    #pragma unroll
    for (int ks = 0; ks < 4; ++ks) {
      bf16x8 a[2];
      #pragma unroll
      for (int mt = 0; mt < 2; ++mt)
        a[mt] = lds_frag(XH + (row0 + mt * 16 + m) * 136 + ks * 32 + q * 8);
      #pragma unroll
      for (int nt = 0; nt < 8; ++nt) {
        bf16x8 b = *reinterpret_cast<const bf16x8*>(w2t + (nt * 16 + m) * 128 + ks * 32 + q * 8);
        #pragma unroll
        for (int mt = 0; mt < 2; ++mt)
          acc[mt][nt] = mfma16(a[mt], b, acc[mt][nt]);
      }
    }
    #pragma unroll
    for (int mt = 0; mt < 2; ++mt)
      #pragma unroll
      for (int nt = 0; nt < 8; ++nt) {
        int col = nt * 16 + m;
        float bb = b2[col];
        #pragma unroll
        for (int r = 0; r < 4; ++r) {
          int row = row0 + mt * 16 + q * 4 + r;
          XH[row * 136 + col] = f2bf(fmaxf(acc[mt][nt][r] + bb, 0.0f));
        }
      }
  }

  // layer 3: H2 @ w3t (+dcon), mask, scatter NHWC
  {
    floatx4 acc[2][2];
    #pragma unroll
    for (int mt = 0; mt < 2; ++mt)
      #pragma unroll
      for (int nt = 0; nt < 2; ++nt)
        #pragma unroll
        for (int r = 0; r < 4; ++r) {
          int row = row0 + mt * 16 + q * 4 + r;
          acc[mt][nt][r] = dcon[(row >> 2) * 32 + nt * 16 + m];
        }
    #pragma unroll
    for (int ks = 0; ks < 4; ++ks) {
      bf16x8 a[2];
      #pragma unroll
      for (int mt = 0; mt < 2; ++mt)
        a[mt] = lds_frag(XH + (row0 + mt * 16 + m) * 136 + ks * 32 + q * 8);
      #pragma unroll
      for (int nt = 0; nt < 2; ++nt) {
        bf16x8 b = *reinterpret_cast<const bf16x8*>(w3t + (nt * 16 + m) * 128 + ks * 32 + q * 8);
        #pragma unroll
        for (int mt = 0; mt < 2; ++mt)
          acc[mt][nt] = mfma16(a[mt], b, acc[mt][nt]);
      }
    }
    #pragma unroll
    for (int mt = 0; mt < 2; ++mt)
      #pragma unroll
      for (int nt = 0; nt < 2; ++nt)
        #pragma unroll
        for (int r = 0; r < 4; ++r) {
          int row = row0 + mt * 16 + q * 4 + r;
          int sg = blockIdx.x * 64 + row;
          int pixel = sg >> 2, p = sg & 3;
          float v = acc[mt][nt][r] * maskv[row];
          rdmp[(size_t)pixel * 128 + p * 32 + nt * 16 + m] = f2bf(v);
        }
  }
}

// ---------------- NHWC 3x3 conv via MFMA ----------------
// WAVES*64 thr, 16x4 output tile. Each wave owns COUT/WAVES couts (NT tiles).
// kc-loop ROLLED (#pragma unroll 1 — round-3 spill lesson); per kc the wave
// caches all 18 halo A-frags a[6][3] in regs (72 VGPRs), then 9 unrolled taps
// do NT coalesced 1KiB B-loads + 4*NT MFMAs each. MFMA:ds_read = 4:1.
// MODE 0: relu -> bf16. MODE 1: sigmoid(acc)*rdmp -> bf16.
template<int CIN, int COUT, int WAVES, int MODE>
__global__ __launch_bounds__(WAVES * 64, 2) void conv3x3(
    const unsigned short* __restrict__ in, const unsigned short* __restrict__ wt,
    const float* __restrict__ bias, const unsigned short* __restrict__ rdmp,
    unsigned short* __restrict__ out) {
  constexpr int CP  = CIN + 8;
  constexpr int CH8 = CIN / 8;
  constexpr int KC  = CIN / 32;
  constexpr int NT  = COUT / (WAVES * 16);
  __shared__ __align__(16) unsigned short lds_in[6 * 18 * CP];

  const int tid = threadIdx.x;
  const int x0 = blockIdx.x * 16, y0 = blockIdx.y * 4;

  for (int i = tid; i < 108 * CH8; i += WAVES * 64) {
    int pix = i / CH8, part = i - pix * CH8;
    int xx = pix % 18, yy = pix / 18;
    int gx = x0 - 1 + xx, gy = y0 - 1 + yy;
    ushort8 v = {0, 0, 0, 0, 0, 0, 0, 0};
    if (gx >= 0 && gx < IMGW && gy >= 0 && gy < IMGW)
      v = *reinterpret_cast<const ushort8*>(in + ((size_t)(gy * IMGW + gx)) * CIN + part * 8);
    *reinterpret_cast<ushort8*>(&lds_in[pix * CP + part * 8]) = v;
  }
  __syncthreads();

  const int wave = tid >> 6, lane = tid & 63, q = lane >> 4, m = lane & 15;
  floatx4 acc[4][NT] = {};

  #pragma unroll 1
  for (int kc = 0; kc < KC; ++kc) {
    // A-fragment register cache: whole 6x18 halo slice for this kc
    bf16x8 a[6][3];
    #pragma unroll
    for (int rr = 0; rr < 6; ++rr)
      #pragma unroll
      for (int dx = 0; dx < 3; ++dx)
        a[rr][dx] = lds_frag(&lds_in[(rr * 18 + m + dx) * CP + kc * 32 + q * 8]);
    #pragma unroll
    for (int nb = 0; nb < 9; ++nb) {
      int dy = nb / 3, dx = nb - dy * 3;
      int ks = nb * KC + kc;
      #pragma unroll
      for (int nt = 0; nt < NT; ++nt) {
        bf16x8 b = *reinterpret_cast<const bf16x8*>(
            wt + ((((size_t)ks * WAVES + wave) * NT + nt) << 9) + lane * 8);
        #pragma unroll
        for (int mt = 0; mt < 4; ++mt)
          acc[mt][nt] = mfma16(a[mt + dy][dx], b, acc[mt][nt]);
      }
    }
  }

  const int co0 = wave * (COUT / WAVES);
  #pragma unroll
  for (int mt = 0; mt < 4; ++mt) {
    int y = y0 + mt;
    #pragma unroll
    for (int nt = 0; nt < NT; ++nt) {
      int co = co0 + nt * 16 + m;
      float bb = bias[co];
      #pragma unroll
      for (int r = 0; r < 4; ++r) {
        int pixel = y * IMGW + x0 + q * 4 + r;
        float v = acc[mt][nt][r] + bb;
        if (MODE == 0) {
          v = fmaxf(v, 0.0f);
        } else {
          v = 1.0f / (1.0f + __expf(-v));
          v *= bf2f(rdmp[(size_t)pixel * 128 + co]);
        }
        out[(size_t)pixel * COUT + co] = f2bf(v);
      }
    }
  }
}

// ---------------- final 64->3 conv + sigmoid, fp32 NHWC out ----------------
__global__ __launch_bounds__(256) void uconv3_kernel(
    const unsigned short* __restrict__ u2, const float* __restrict__ w,
    const float* __restrict__ b, float* __restrict__ out) {
  __shared__ float wl[1728];   // [nb][ci][c]
  for (int i = threadIdx.x; i < 1728; i += 256) {
    int c = i % 3; int t = i / 3; int ci = t & 63; int nb = t >> 6;
    wl[i] = w[(c * 64 + ci) * 9 + nb];
  }
  __syncthreads();
  int pixel = blockIdx.x * 256 + threadIdx.x;
  int py = pixel / IMGW, px = pixel - py * IMGW;
  float a0 = b[0], a1 = b[1], a2 = b[2];
  for (int nb = 0; nb < 9; ++nb) {
    int gy = py + nb / 3 - 1, gx = px + nb % 3 - 1;
    if (gx < 0 || gx >= IMGW || gy < 0 || gy >= IMGW) continue;
    const unsigned short* src = u2 + (size_t)(gy * IMGW + gx) * 64;
    const float* wp = wl + nb * 192;
    #pragma unroll
    for (int cc = 0; cc < 8; ++cc) {
      ushort8 v = *reinterpret_cast<const ushort8*>(src + cc * 8);
      #pragma unroll
      for (int j = 0; j < 8; ++j) {
        float uv = bf2f(v[j]);
        const float* w3p = wp + (cc * 8 + j) * 3;
        a0 += uv * w3p[0]; a1 += uv * w3p[1]; a2 += uv * w3p[2];
      }
    }
  }
  float* o = out + (size_t)pixel * 3;
  o[0] = 1.0f / (1.0f + __expf(-a0));
  o[1] = 1.0f / (1.0f + __expf(-a1));
  o[2] = 1.0f / (1.0f + __expf(-a2));
}

extern "C" void kernel_launch(void* const* d_in, const int* in_sizes, int n_in,
                              void* d_out, int out_size, void* d_ws, size_t ws_size,
                              hipStream_t stream) {
  (void)in_sizes; (void)n_in; (void)out_size; (void)ws_size;
  const float* zbufs = (const float*)d_in[0];
  const float* ray   = (const float*)d_in[1];
  const int* isTrain = (const int*)d_in[4];
  const float* w1 = (const float*)d_in[6];
  const float* b1 = (const float*)d_in[7];
  const float* w2 = (const float*)d_in[8];
  const float* b2 = (const float*)d_in[9];
  const float* w3 = (const float*)d_in[10];
  const float* b3 = (const float*)d_in[11];
  const float* mpn_w1 = (const float*)d_in[12];
  const float* mpn_b1 = (const float*)d_in[13];
  const float* mpn_w2 = (const float*)d_in[14];
  const float* mpn_b2 = (const float*)d_in[15];
  const float* uw1 = (const float*)d_in[16];
  const float* ub1 = (const float*)d_in[17];
  const float* uw2 = (const float*)d_in[18];
  const float* ub2 = (const float*)d_in[19];
  const float* uw3 = (const float*)d_in[20];
  const float* ub3 = (const float*)d_in[21];
  float* out = (float*)d_out;

  unsigned char* ws = (unsigned char*)d_ws;
  size_t off = 0;
  auto alloc = [&](size_t bytes) -> void* {
    void* p = ws + off; off = (off + bytes + 255) & ~(size_t)255; return p;
  };
  unsigned short* w1t  = (unsigned short*)alloc(8192 * 2);
  unsigned short* w2t  = (unsigned short*)alloc(16384 * 2);
  unsigned short* w3t  = (unsigned short*)alloc(4096 * 2);
  unsigned short* cw1  = (unsigned short*)alloc((size_t)128 * 1152 * 2);
  unsigned short* cw2  = (unsigned short*)alloc((size_t)128 * 1152 * 2);
  unsigned short* cu1  = (unsigned short*)alloc((size_t)64 * 1152 * 2);
  unsigned short* cu2  = (unsigned short*)alloc((size_t)64 * 576 * 2);
  unsigned short* rdmp = (unsigned short*)alloc((size_t)NPIX * 128 * 2);
  unsigned short* t1   = (unsigned short*)alloc((size_t)NPIX * 128 * 2);
  unsigned short* fuse = (unsigned short*)alloc((size_t)NPIX * 128 * 2);
  unsigned short* u1 = t1;            // t1 dead after conv2
  unsigned short* u2 = rdmp;          // rdmp dead after conv2 (fuse epilogue)
  float* dconG = (float*)fuse;        // dconG dead before conv2 writes fuse

  prep_mlp<<<112, 256, 0, stream>>>(w1, w2, w3, w1t, w2t, w3t);
  prep_convB<<<576, 256, 0, stream>>>(mpn_w1, cw1, 128 * 1152, 128, 4, 2);
  prep_convB<<<576, 256, 0, stream>>>(mpn_w2, cw2, 128 * 1152, 128, 4, 2);
  prep_convB<<<288, 256, 0, stream>>>(uw1, cu1, 64 * 1152, 128, 2, 2);
  prep_convB<<<144, 256, 0, stream>>>(uw2, cu2, 64 * 576, 64, 2, 2);

  dcon_kernel<<<NPIX * 32 / 256, 256, 0, stream>>>(ray, w3, b3, dconG);
  mlp_kernel<<<NPIX * 4 / 64, 128, 0, stream>>>(zbufs, ray, isTrain, b1, b2,
                                                w1t, w2t, w3t, dconG, rdmp);

  dim3 cgrid(IMGW / 16, IMGW / 4);
  conv3x3<128, 128, 4, 0><<<cgrid, 256, 0, stream>>>(rdmp, cw1, mpn_b1, nullptr, t1);
  conv3x3<128, 128, 4, 1><<<cgrid, 256, 0, stream>>>(t1, cw2, mpn_b2, rdmp, fuse);
  conv3x3<128, 64, 2, 0><<<cgrid, 128, 0, stream>>>(fuse, cu1, ub1, nullptr, u1);
  conv3x3<64, 64, 2, 0><<<cgrid, 128, 0, stream>>>(u1, cu2, ub2, nullptr, u2);
  uconv3_kernel<<<NPIX / 256, 256, 0, stream>>>(u2, uw3, ub3, out);
}

// Round 5
// 374.577 us; speedup vs baseline: 3.1558x; 1.1819x over previous
//
#include <hip/hip_runtime.h>
#include <hip/hip_bf16.h>
#include <math.h>

typedef __attribute__((ext_vector_type(8))) unsigned short ushort8;
typedef __attribute__((ext_vector_type(8))) __bf16 bf16x8;
typedef __attribute__((ext_vector_type(4))) float floatx4;

constexpr int IMGW = 384;
constexpr int NPIX = IMGW * IMGW;

__device__ __forceinline__ unsigned short f2bf(float f) {
  union { float f; unsigned u; } v; v.f = f;
  unsigned u = v.u;
  return (unsigned short)((u + 0x7fffu + ((u >> 16) & 1u)) >> 16);
}
__device__ __forceinline__ float bf2f(unsigned short h) {
  union { unsigned u; float f; } v; v.u = ((unsigned)h) << 16; return v.f;
}
// pack 2 fp32 -> 2 bf16 (RNE) in one dword; lowers to v_cvt_pk_bf16_f32 on gfx950
__device__ __forceinline__ unsigned pk2bf(float a, float b) {
  float2 f2; f2.x = a; f2.y = b;
  __hip_bfloat162 h = __float22bfloat162_rn(f2);
  union { __hip_bfloat162 h; unsigned u; } u; u.h = h; return u.u;
}
__device__ __forceinline__ floatx4 mfma16(bf16x8 a, bf16x8 b, floatx4 c) {
  return __builtin_amdgcn_mfma_f32_16x16x32_bf16(a, b, c, 0, 0, 0);
}
__device__ __forceinline__ bf16x8 lds_frag(const unsigned short* p) {
  return *reinterpret_cast<const bf16x8*>(p);
}

// ---------------- weight prep: MLP A-operand, swizzle-packed ----------------
// wA[(mt*KS+ks)*512 + lane*8 + j] = W[k][ch], ch=mt*16+(lane&15), k=ks*32+(lane>>4)*8+j
// One wave A-frag = contiguous coalesced 1 KiB.
__global__ void prep_mlpA(const float* __restrict__ w1, const float* __restrict__ w2,
                          const float* __restrict__ w3,
                          unsigned short* __restrict__ w1A, unsigned short* __restrict__ w2A,
                          unsigned short* __restrict__ w3A) {
  int i = blockIdx.x * 256 + threadIdx.x;
  if (i < 8192) {                       // w1A: M=128 (mt 8), KS=2
    int j = i & 7, lane = (i >> 3) & 63, t = i >> 9;
    int mt = t >> 1, ks = t & 1;
    int ch = mt * 16 + (lane & 15), k = ks * 32 + (lane >> 4) * 8 + j;
    w1A[i] = f2bf(k < 63 ? w1[k * 128 + ch] : 0.0f);
  } else if (i < 24576) {               // w2A: M=128 (mt 8), KS=4
    int i2 = i - 8192;
    int j = i2 & 7, lane = (i2 >> 3) & 63, t = i2 >> 9;
    int mt = t >> 2, ks = t & 3;
    int ch = mt * 16 + (lane & 15), k = ks * 32 + (lane >> 4) * 8 + j;
    w2A[i2] = f2bf(w2[k * 128 + ch]);
  } else if (i < 28672) {               // w3A: M=32 (mt 2), KS=4
    int i3 = i - 24576;
    int j = i3 & 7, lane = (i3 >> 3) & 63, t = i3 >> 9;
    int mt = t >> 2, ks = t & 3;
    int ch = mt * 16 + (lane & 15), k = ks * 32 + (lane >> 4) * 8 + j;
    w3A[i3] = f2bf(w3[k * 32 + ch]);
  }
}

// OIHW fp32 -> swizzled conv B: flat idx = ((ks*G + g)*NT + nt)*512 + lane*8 + j
__global__ void prep_convB(const float* __restrict__ w, unsigned short* __restrict__ wt,
                           int total, int CIN, int G, int NT) {
  int i = blockIdx.x * 256 + threadIdx.x;
  if (i >= total) return;
  int j = i & 7, lane = (i >> 3) & 63;
  int rest = i >> 9;
  int nt = rest % NT; int rest2 = rest / NT;
  int g = rest2 % G;  int ks = rest2 / G;
  int q = lane >> 4, m = lane & 15;
  int co = (g * NT + nt) * 16 + m;
  int k = ks * 32 + q * 8 + j;
  int nb = k / CIN, ci = k - nb * CIN;
  wt[i] = f2bf(w[(co * CIN + ci) * 9 + nb]);
}

// ---------------- per-pixel dir-PE contribution: dconG[pixel][32] ----------------
__global__ __launch_bounds__(256) void dcon_kernel(
    const float* __restrict__ ray, const float* __restrict__ w3,
    const float* __restrict__ b3, float* __restrict__ dconG) {
  int gid = blockIdx.x * 256 + threadIdx.x;
  int pixel = gid >> 5, c = gid & 31;
  const float* r = ray + (size_t)pixel * 7;
  float d0 = r[3], d1 = r[4], d2 = r[5];
  float acc = b3[c];
  acc += d0 * w3[128 * 32 + c] + d1 * w3[129 * 32 + c] + d2 * w3[130 * 32 + c];
  float dv[3] = { d0, d1, d2 };
  #pragma unroll
  for (int cc = 0; cc < 3; ++cc) {
    float fs = 1.0f;
    #pragma unroll
    for (int f = 0; f < 4; ++f) {
      float s, co;
      __sincosf(dv[cc] * fs, &s, &co);
      acc += s * w3[(131 + cc * 4 + f) * 32 + c];
      acc += co * w3[(143 + cc * 4 + f) * 32 + c];
      fs *= 2.0f;
    }
  }
  dconG[gid] = acc;
}

// ---------------- fused per-sample MLP (transposed orientation) ----------------
// 128 thr (2 waves), 64 samples/block; wave w owns samples w*32..w*32+31 ONLY
// -> zero __syncthreads. Each layer computes D^T = W(A) x H(B): C-frag lane
// holds 4 consecutive CHANNELS of one sample -> ds_write_b64 epilogues.
// X lives in H rows cols 0..63 (overwritten by L1 epilogue, in-wave in-order).
// LDS: H 64*136*2=17408 + dcon 2048 + mask 256 = 19712 B.
__global__ __launch_bounds__(128, 3) void mlp_kernel(
    const float* __restrict__ zbufs, const float* __restrict__ ray,
    const int* __restrict__ isTrain,
    const float* __restrict__ b1, const float* __restrict__ b2,
    const unsigned short* __restrict__ w1A, const unsigned short* __restrict__ w2A,
    const unsigned short* __restrict__ w3A, const float* __restrict__ dconG,
    unsigned short* __restrict__ rdmp) {
  __shared__ __align__(16) unsigned short H[64 * 136];
  __shared__ __align__(16) float dcon[16 * 32];
  __shared__ float maskv[64];

  const int tid = threadIdx.x;
  const int wave = tid >> 6, lane = tid & 63, q = lane >> 4, m = lane & 15;
  const int s0 = wave * 32;
  const float thresh = (isTrain[0] != 0) ? 0.2f : 0.0f;

  // phase 0: PE (2 threads/sample, f-split); wave writes only its own rows
  {
    int s = s0 + (lane >> 1), h = lane & 1;
    int sg = blockIdx.x * 64 + s;
    int pixel = sg >> 2;
    float z = zbufs[sg];
    const float* r = ray + (size_t)pixel * 7;
    float t = z / r[6];
    float xv[3] = { r[0] + r[3] * t, r[1] + r[4] * t, r[2] + r[5] * t };
    unsigned short* Xr = H + s * 136;
    if (h == 0) {
      maskv[s] = (z > thresh) ? 1.0f : 0.0f;
      Xr[0] = f2bf(xv[0]); Xr[1] = f2bf(xv[1]); Xr[2] = f2bf(xv[2]);
      Xr[63] = 0;
    }
    float fb = h ? 32.0f : 1.0f;
    int fo = h * 5;
    #pragma unroll
    for (int c = 0; c < 3; ++c)
      #pragma unroll
      for (int fi = 0; fi < 5; ++fi) {
        float s_, c_;
        __sincosf(xv[c] * (fb * (float)(1 << fi)), &s_, &c_);
        Xr[3 + c * 10 + fo + fi]  = f2bf(s_);
        Xr[33 + c * 10 + fo + fi] = f2bf(c_);
      }
  }
  // stage dcon: wave w stages its own 8 pixels (256 floats), coalesced
  {
    const float* src = dconG + (size_t)blockIdx.x * 512 + wave * 256;
    *reinterpret_cast<float4*>(&dcon[wave * 256 + lane * 4]) =
        *reinterpret_cast<const float4*>(src + lane * 4);
  }
  // no barrier: all LDS regions wave-private, LDS is in-order per wave

  // ---- layer 1: D^T = w1A(128xK64) x X(B) -> H (relu) ----
  {
    floatx4 acc[8][2] = {};
    #pragma unroll 1
    for (int ks = 0; ks < 2; ++ks) {
      bf16x8 a[8];
      #pragma unroll
      for (int mt = 0; mt < 8; ++mt)
        a[mt] = *reinterpret_cast<const bf16x8*>(w1A + (((mt << 1) + ks) << 9) + lane * 8);
      bf16x8 bf[2];
      #pragma unroll
      for (int nt = 0; nt < 2; ++nt)
        bf[nt] = lds_frag(H + (s0 + nt * 16 + m) * 136 + ks * 32 + q * 8);
      #pragma unroll
      for (int mt = 0; mt < 8; ++mt)
        #pragma unroll
        for (int nt = 0; nt < 2; ++nt)
          acc[mt][nt] = mfma16(a[mt], bf[nt], acc[mt][nt]);
    }
    #pragma unroll
    for (int mt = 0; mt < 8; ++mt) {
      float4 bb = *reinterpret_cast<const float4*>(b1 + mt * 16 + q * 4);
      #pragma unroll
      for (int nt = 0; nt < 2; ++nt) {
        float v0 = fmaxf(acc[mt][nt][0] + bb.x, 0.0f);
        float v1 = fmaxf(acc[mt][nt][1] + bb.y, 0.0f);
        float v2 = fmaxf(acc[mt][nt][2] + bb.z, 0.0f);
        float v3 = fmaxf(acc[mt][nt][3] + bb.w, 0.0f);
        uint2 pk; pk.x = pk2bf(v0, v1); pk.y = pk2bf(v2, v3);
        *reinterpret_cast<uint2*>(&H[(s0 + nt * 16 + m) * 136 + mt * 16 + q * 4]) = pk;
      }
    }
  }

  // ---- layer 2: D^T = w2A(128x128) x H1(B) -> H (relu), in place ----
  {
    floatx4 acc[8][2] = {};
    #pragma unroll 1
    for (int ks = 0; ks < 4; ++ks) {
      bf16x8 a[8];
      #pragma unroll
      for (int mt = 0; mt < 8; ++mt)
        a[mt] = *reinterpret_cast<const bf16x8*>(w2A + (((mt << 2) + ks) << 9) + lane * 8);
      bf16x8 bf[2];
      #pragma unroll
      for (int nt = 0; nt < 2; ++nt)
        bf[nt] = lds_frag(H + (s0 + nt * 16 + m) * 136 + ks * 32 + q * 8);
      #pragma unroll
      for (int mt = 0; mt < 8; ++mt)
        #pragma unroll
        for (int nt = 0; nt < 2; ++nt)
          acc[mt][nt] = mfma16(a[mt], bf[nt], acc[mt][nt]);
    }
    #pragma unroll
    for (int mt = 0; mt < 8; ++mt) {
      float4 bb = *reinterpret_cast<const float4*>(b2 + mt * 16 + q * 4);
      #pragma unroll
      for (int nt = 0; nt < 2; ++nt) {
        float v0 = fmaxf(acc[mt][nt][0] + bb.x, 0.0f);
        float v1 = fmaxf(acc[mt][nt][1] + bb.y, 0.0f);
        float v2 = fmaxf(acc[mt][nt][2] + bb.z, 0.0f);
        float v3 = fmaxf(acc[mt][nt][3] + bb.w, 0.0f);
        uint2 pk; pk.x = pk2bf(v0, v1); pk.y = pk2bf(v2, v3);
        *reinterpret_cast<uint2*>(&H[(s0 + nt * 16 + m) * 136 + mt * 16 + q * 4]) = pk;
      }
    }
  }

  // ---- layer 3: D^T = w3A(32x128) x H2(B) (+dcon), mask, coalesced NHWC ----
  {
    floatx4 acc[2][2];
    #pragma unroll
    for (int mt = 0; mt < 2; ++mt)
      #pragma unroll
      for (int nt = 0; nt < 2; ++nt) {
        int s = s0 + nt * 16 + m;
        acc[mt][nt] = *reinterpret_cast<const floatx4*>(
            &dcon[(s >> 2) * 32 + mt * 16 + q * 4]);
      }
    #pragma unroll 1
    for (int ks = 0; ks < 4; ++ks) {
      bf16x8 a[2];
      #pragma unroll
      for (int mt = 0; mt < 2; ++mt)
        a[mt] = *reinterpret_cast<const bf16x8*>(w3A + (((mt << 2) + ks) << 9) + lane * 8);
      bf16x8 bf[2];
      #pragma unroll
      for (int nt = 0; nt < 2; ++nt)
        bf[nt] = lds_frag(H + (s0 + nt * 16 + m) * 136 + ks * 32 + q * 8);
      #pragma unroll
      for (int mt = 0; mt < 2; ++mt)
        #pragma unroll
        for (int nt = 0; nt < 2; ++nt)
          acc[mt][nt] = mfma16(a[mt], bf[nt], acc[mt][nt]);
    }
    // rdmp offset: pixel*128 + p*32 + ch  ==  blk*2048 + s*32 + ch
    #pragma unroll
    for (int nt = 0; nt < 2; ++nt) {
      int s = s0 + nt * 16 + m;
      float mk = maskv[s];
      unsigned short* dst = rdmp + (size_t)blockIdx.x * 2048 + s * 32 + q * 4;
      #pragma unroll
      for (int mt = 0; mt < 2; ++mt) {
        uint2 pk;
        pk.x = pk2bf(acc[mt][nt][0] * mk, acc[mt][nt][1] * mk);
        pk.y = pk2bf(acc[mt][nt][2] * mk, acc[mt][nt][3] * mk);
        *reinterpret_cast<uint2*>(dst + mt * 16) = pk;
      }
    }
  }
}

// ---------------- NHWC 3x3 conv via MFMA (unchanged from round 4) ----------------
template<int CIN, int COUT, int WAVES, int MODE>
__global__ __launch_bounds__(WAVES * 64, 2) void conv3x3(
    const unsigned short* __restrict__ in, const unsigned short* __restrict__ wt,
    const float* __restrict__ bias, const unsigned short* __restrict__ rdmp,
    unsigned short* __restrict__ out) {
  constexpr int CP  = CIN + 8;
  constexpr int CH8 = CIN / 8;
  constexpr int KC  = CIN / 32;
  constexpr int NT  = COUT / (WAVES * 16);
  __shared__ __align__(16) unsigned short lds_in[6 * 18 * CP];

  const int tid = threadIdx.x;
  const int x0 = blockIdx.x * 16, y0 = blockIdx.y * 4;

  for (int i = tid; i < 108 * CH8; i += WAVES * 64) {
    int pix = i / CH8, part = i - pix * CH8;
    int xx = pix % 18, yy = pix / 18;
    int gx = x0 - 1 + xx, gy = y0 - 1 + yy;
    ushort8 v = {0, 0, 0, 0, 0, 0, 0, 0};
    if (gx >= 0 && gx < IMGW && gy >= 0 && gy < IMGW)
      v = *reinterpret_cast<const ushort8*>(in + ((size_t)(gy * IMGW + gx)) * CIN + part * 8);
    *reinterpret_cast<ushort8*>(&lds_in[pix * CP + part * 8]) = v;
  }
  __syncthreads();

  const int wave = tid >> 6, lane = tid & 63, q = lane >> 4, m = lane & 15;
  floatx4 acc[4][NT] = {};

  #pragma unroll 1
  for (int kc = 0; kc < KC; ++kc) {
    bf16x8 a[6][3];
    #pragma unroll
    for (int rr = 0; rr < 6; ++rr)
      #pragma unroll
      for (int dx = 0; dx < 3; ++dx)
        a[rr][dx] = lds_frag(&lds_in[(rr * 18 + m + dx) * CP + kc * 32 + q * 8]);
    #pragma unroll
    for (int nb = 0; nb < 9; ++nb) {
      int dy = nb / 3, dx = nb - dy * 3;
      int ks = nb * KC + kc;
      #pragma unroll
      for (int nt = 0; nt < NT; ++nt) {
        bf16x8 b = *reinterpret_cast<const bf16x8*>(
            wt + ((((size_t)ks * WAVES + wave) * NT + nt) << 9) + lane * 8);
        #pragma unroll
        for (int mt = 0; mt < 4; ++mt)
          acc[mt][nt] = mfma16(a[mt + dy][dx], b, acc[mt][nt]);
      }
    }
  }

  const int co0 = wave * (COUT / WAVES);
  #pragma unroll
  for (int mt = 0; mt < 4; ++mt) {
    int y = y0 + mt;
    #pragma unroll
    for (int nt = 0; nt < NT; ++nt) {
      int co = co0 + nt * 16 + m;
      float bb = bias[co];
      #pragma unroll
      for (int r = 0; r < 4; ++r) {
        int pixel = y * IMGW + x0 + q * 4 + r;
        float v = acc[mt][nt][r] + bb;
        if (MODE == 0) {
          v = fmaxf(v, 0.0f);
        } else {
          v = 1.0f / (1.0f + __expf(-v));
          v *= bf2f(rdmp[(size_t)pixel * 128 + co]);
        }
        out[(size_t)pixel * COUT + co] = f2bf(v);
      }
    }
  }
}

// ---------------- final 64->3 conv + sigmoid, fp32 NHWC out ----------------
__global__ __launch_bounds__(256) void uconv3_kernel(
    const unsigned short* __restrict__ u2, const float* __restrict__ w,
    const float* __restrict__ b, float* __restrict__ out) {
  __shared__ float wl[1728];   // [nb][ci][c]
  for (int i = threadIdx.x; i < 1728; i += 256) {
    int c = i % 3; int t = i / 3; int ci = t & 63; int nb = t >> 6;
    wl[i] = w[(c * 64 + ci) * 9 + nb];
  }
  __syncthreads();
  int pixel = blockIdx.x * 256 + threadIdx.x;
  int py = pixel / IMGW, px = pixel - py * IMGW;
  float a0 = b[0], a1 = b[1], a2 = b[2];
  for (int nb = 0; nb < 9; ++nb) {
    int gy = py + nb / 3 - 1, gx = px + nb % 3 - 1;
    if (gx < 0 || gx >= IMGW || gy < 0 || gy >= IMGW) continue;
    const unsigned short* src = u2 + (size_t)(gy * IMGW + gx) * 64;
    const float* wp = wl + nb * 192;
    #pragma unroll
    for (int cc = 0; cc < 8; ++cc) {
      ushort8 v = *reinterpret_cast<const ushort8*>(src + cc * 8);
      #pragma unroll
      for (int j = 0; j < 8; ++j) {
        float uv = bf2f(v[j]);
        const float* w3p = wp + (cc * 8 + j) * 3;
        a0 += uv * w3p[0]; a1 += uv * w3p[1]; a2 += uv * w3p[2];
      }
    }
  }
  float* o = out + (size_t)pixel * 3;
  o[0] = 1.0f / (1.0f + __expf(-a0));
  o[1] = 1.0f / (1.0f + __expf(-a1));
  o[2] = 1.0f / (1.0f + __expf(-a2));
}

extern "C" void kernel_launch(void* const* d_in, const int* in_sizes, int n_in,
                              void* d_out, int out_size, void* d_ws, size_t ws_size,
                              hipStream_t stream) {
  (void)in_sizes; (void)n_in; (void)out_size; (void)ws_size;
  const float* zbufs = (const float*)d_in[0];
  const float* ray   = (const float*)d_in[1];
  const int* isTrain = (const int*)d_in[4];
  const float* w1 = (const float*)d_in[6];
  const float* b1 = (const float*)d_in[7];
  const float* w2 = (const float*)d_in[8];
  const float* b2 = (const float*)d_in[9];
  const float* w3 = (const float*)d_in[10];
  const float* b3 = (const float*)d_in[11];
  const float* mpn_w1 = (const float*)d_in[12];
  const float* mpn_b1 = (const float*)d_in[13];
  const float* mpn_w2 = (const float*)d_in[14];
  const float* mpn_b2 = (const float*)d_in[15];
  const float* uw1 = (const float*)d_in[16];
  const float* ub1 = (const float*)d_in[17];
  const float* uw2 = (const float*)d_in[18];
  const float* ub2 = (const float*)d_in[19];
  const float* uw3 = (const float*)d_in[20];
  const float* ub3 = (const float*)d_in[21];
  float* out = (float*)d_out;

  unsigned char* ws = (unsigned char*)d_ws;
  size_t off = 0;
  auto alloc = [&](size_t bytes) -> void* {
    void* p = ws + off; off = (off + bytes + 255) & ~(size_t)255; return p;
  };
  unsigned short* w1A  = (unsigned short*)alloc(8192 * 2);
  unsigned short* w2A  = (unsigned short*)alloc(16384 * 2);
  unsigned short* w3A  = (unsigned short*)alloc(4096 * 2);
  unsigned short* cw1  = (unsigned short*)alloc((size_t)128 * 1152 * 2);
  unsigned short* cw2  = (unsigned short*)alloc((size_t)128 * 1152 * 2);
  unsigned short* cu1  = (unsigned short*)alloc((size_t)64 * 1152 * 2);
  unsigned short* cu2  = (unsigned short*)alloc((size_t)64 * 576 * 2);
  unsigned short* rdmp = (unsigned short*)alloc((size_t)NPIX * 128 * 2);
  unsigned short* t1   = (unsigned short*)alloc((size_t)NPIX * 128 * 2);
  unsigned short* fuse = (unsigned short*)alloc((size_t)NPIX * 128 * 2);
  unsigned short* u1 = t1;            // t1 dead after conv2
  unsigned short* u2 = rdmp;          // rdmp dead after conv2 (fuse epilogue)
  float* dconG = (float*)fuse;        // dconG dead before conv2 writes fuse

  prep_mlpA<<<112, 256, 0, stream>>>(w1, w2, w3, w1A, w2A, w3A);
  prep_convB<<<576, 256, 0, stream>>>(mpn_w1, cw1, 128 * 1152, 128, 4, 2);
  prep_convB<<<576, 256, 0, stream>>>(mpn_w2, cw2, 128 * 1152, 128, 4, 2);
  prep_convB<<<288, 256, 0, stream>>>(uw1, cu1, 64 * 1152, 128, 2, 2);
  prep_convB<<<144, 256, 0, stream>>>(uw2, cu2, 64 * 576, 64, 2, 2);

  dcon_kernel<<<NPIX * 32 / 256, 256, 0, stream>>>(ray, w3, b3, dconG);
  mlp_kernel<<<NPIX * 4 / 64, 128, 0, stream>>>(zbufs, ray, isTrain, b1, b2,
                                                w1A, w2A, w3A, dconG, rdmp);

  dim3 cgrid(IMGW / 16, IMGW / 4);
  conv3x3<128, 128, 4, 0><<<cgrid, 256, 0, stream>>>(rdmp, cw1, mpn_b1, nullptr, t1);
  conv3x3<128, 128, 4, 1><<<cgrid, 256, 0, stream>>>(t1, cw2, mpn_b2, rdmp, fuse);
  conv3x3<128, 64, 2, 0><<<cgrid, 128, 0, stream>>>(fuse, cu1, ub1, nullptr, u1);
  conv3x3<64, 64, 2, 0><<<cgrid, 128, 0, stream>>>(u1, cu2, ub2, nullptr, u2);
  uconv3_kernel<<<NPIX / 256, 256, 0, stream>>>(u2, uw3, ub3, out);
}

// Round 6
// 365.311 us; speedup vs baseline: 3.2358x; 1.0254x over previous
//
#include <hip/hip_runtime.h>
#include <hip/hip_bf16.h>
#include <math.h>

typedef __attribute__((ext_vector_type(8))) unsigned short ushort8;
typedef __attribute__((ext_vector_type(8))) __bf16 bf16x8;
typedef __attribute__((ext_vector_type(4))) float floatx4;

constexpr int IMGW = 384;
constexpr int NPIX = IMGW * IMGW;

__device__ __forceinline__ unsigned short f2bf(float f) {
  union { float f; unsigned u; } v; v.f = f;
  unsigned u = v.u;
  return (unsigned short)((u + 0x7fffu + ((u >> 16) & 1u)) >> 16);
}
__device__ __forceinline__ float bf2f(unsigned short h) {
  union { unsigned u; float f; } v; v.u = ((unsigned)h) << 16; return v.f;
}
// pack 2 fp32 -> 2 bf16 (RNE): v_cvt_pk_bf16_f32
__device__ __forceinline__ unsigned pk2bf(float a, float b) {
  float2 f2; f2.x = a; f2.y = b;
  __hip_bfloat162 h = __float22bfloat162_rn(f2);
  union { __hip_bfloat162 h; unsigned u; } u; u.h = h; return u.u;
}
// single fp32 -> bf16 (RNE), 1 VALU op
__device__ __forceinline__ unsigned short cvt1bf(float a) {
  return (unsigned short)pk2bf(a, a);
}
__device__ __forceinline__ floatx4 mfma16(bf16x8 a, bf16x8 b, floatx4 c) {
  return __builtin_amdgcn_mfma_f32_16x16x32_bf16(a, b, c, 0, 0, 0);
}
__device__ __forceinline__ bf16x8 lds_frag(const unsigned short* p) {
  return *reinterpret_cast<const bf16x8*>(p);
}

// ---------------- weight prep: MLP A-operand, swizzle-packed ----------------
__global__ void prep_mlpA(const float* __restrict__ w1, const float* __restrict__ w2,
                          const float* __restrict__ w3,
                          unsigned short* __restrict__ w1A, unsigned short* __restrict__ w2A,
                          unsigned short* __restrict__ w3A) {
  int i = blockIdx.x * 256 + threadIdx.x;
  if (i < 8192) {                       // w1A: M=128 (mt 8), KS=2
    int j = i & 7, lane = (i >> 3) & 63, t = i >> 9;
    int mt = t >> 1, ks = t & 1;
    int ch = mt * 16 + (lane & 15), k = ks * 32 + (lane >> 4) * 8 + j;
    w1A[i] = f2bf(k < 63 ? w1[k * 128 + ch] : 0.0f);
  } else if (i < 24576) {               // w2A: M=128 (mt 8), KS=4
    int i2 = i - 8192;
    int j = i2 & 7, lane = (i2 >> 3) & 63, t = i2 >> 9;
    int mt = t >> 2, ks = t & 3;
    int ch = mt * 16 + (lane & 15), k = ks * 32 + (lane >> 4) * 8 + j;
    w2A[i2] = f2bf(w2[k * 128 + ch]);
  } else if (i < 28672) {               // w3A: M=32 (mt 2), KS=4
    int i3 = i - 24576;
    int j = i3 & 7, lane = (i3 >> 3) & 63, t = i3 >> 9;
    int mt = t >> 2, ks = t & 3;
    int ch = mt * 16 + (lane & 15), k = ks * 32 + (lane >> 4) * 8 + j;
    w3A[i3] = f2bf(w3[k * 32 + ch]);
  }
}

// OIHW fp32 -> swizzled conv B: flat idx = ((ks*G + g)*NT + nt)*512 + lane*8 + j
__global__ void prep_convB(const float* __restrict__ w, unsigned short* __restrict__ wt,
                           int total, int CIN, int G, int NT) {
  int i = blockIdx.x * 256 + threadIdx.x;
  if (i >= total) return;
  int j = i & 7, lane = (i >> 3) & 63;
  int rest = i >> 9;
  int nt = rest % NT; int rest2 = rest / NT;
  int g = rest2 % G;  int ks = rest2 / G;
  int q = lane >> 4, m = lane & 15;
  int co = (g * NT + nt) * 16 + m;
  int k = ks * 32 + q * 8 + j;
  int nb = k / CIN, ci = k - nb * CIN;
  wt[i] = f2bf(w[(co * CIN + ci) * 9 + nb]);
}

// ---------------- per-pixel dir-PE contribution: dconG[pixel][32] ----------------
__global__ __launch_bounds__(256) void dcon_kernel(
    const float* __restrict__ ray, const float* __restrict__ w3,
    const float* __restrict__ b3, float* __restrict__ dconG) {
  int gid = blockIdx.x * 256 + threadIdx.x;
  int pixel = gid >> 5, c = gid & 31;
  const float* r = ray + (size_t)pixel * 7;
  float d0 = r[3], d1 = r[4], d2 = r[5];
  float acc = b3[c];
  acc += d0 * w3[128 * 32 + c] + d1 * w3[129 * 32 + c] + d2 * w3[130 * 32 + c];
  float dv[3] = { d0, d1, d2 };
  #pragma unroll
  for (int cc = 0; cc < 3; ++cc) {
    float fs = 1.0f;
    #pragma unroll
    for (int f = 0; f < 4; ++f) {
      float s, co;
      __sincosf(dv[cc] * fs, &s, &co);
      acc += s * w3[(131 + cc * 4 + f) * 32 + c];
      acc += co * w3[(143 + cc * 4 + f) * 32 + c];
      fs *= 2.0f;
    }
  }
  dconG[gid] = acc;
}

// ---------------- fused per-sample MLP (transposed orientation) ----------------
// 128 thr (2 waves), 64 samples/block; wave w owns samples w*32..w*32+31 ONLY
// -> zero __syncthreads. LDS = H only (17408 B) -> 8 blocks/CU (16 waves).
// dcon read direct from global (L2-hot); mask recomputed from zbufs (L1-hot).
__global__ __launch_bounds__(128, 4) void mlp_kernel(
    const float* __restrict__ zbufs, const float* __restrict__ ray,
    const int* __restrict__ isTrain,
    const float* __restrict__ b1, const float* __restrict__ b2,
    const unsigned short* __restrict__ w1A, const unsigned short* __restrict__ w2A,
    const unsigned short* __restrict__ w3A, const float* __restrict__ dconG,
    unsigned short* __restrict__ rdmp) {
  __shared__ __align__(16) unsigned short H[64 * 136];

  const int tid = threadIdx.x;
  const int wave = tid >> 6, lane = tid & 63, q = lane >> 4, m = lane & 15;
  const int s0 = wave * 32;
  const float thresh = (isTrain[0] != 0) ? 0.2f : 0.0f;

  // phase 0: PE (2 threads/sample, f-split); double-angle recurrence,
  // 1-op bf16 converts. Wave writes only its own rows.
  {
    int s = s0 + (lane >> 1), h = lane & 1;
    int sg = blockIdx.x * 64 + s;
    int pixel = sg >> 2;
    float z = zbufs[sg];
    const float* r = ray + (size_t)pixel * 7;
    float t = z / r[6];
    float xv[3] = { r[0] + r[3] * t, r[1] + r[4] * t, r[2] + r[5] * t };
    unsigned short* Xr = H + s * 136;
    if (h == 0) {
      Xr[0] = cvt1bf(xv[0]); Xr[1] = cvt1bf(xv[1]); Xr[2] = cvt1bf(xv[2]);
      Xr[63] = 0;
    }
    float fb = h ? 32.0f : 1.0f;
    int fo = h * 5;
    #pragma unroll
    for (int c = 0; c < 3; ++c) {
      float s_, c_;
      __sincosf(xv[c] * fb, &s_, &c_);
      #pragma unroll
      for (int fi = 0; fi < 5; ++fi) {
        Xr[3 + c * 10 + fo + fi]  = cvt1bf(s_);
        Xr[33 + c * 10 + fo + fi] = cvt1bf(c_);
        float t2 = s_ + s_;
        float ns = t2 * c_;
        float nc = fmaf(-t2, s_, 1.0f);   // cos(2x) = 1 - 2 sin^2 x
        s_ = ns; c_ = nc;
      }
    }
  }
  // no barrier: H rows are wave-private; LDS is in-order per wave

  // ---- layer 1: D^T = w1A(128xK64) x X(B) -> H (relu) ----
  {
    floatx4 acc[8][2] = {};
    #pragma unroll 1
    for (int ks = 0; ks < 2; ++ks) {
      bf16x8 a[8];
      #pragma unroll
      for (int mt = 0; mt < 8; ++mt)
        a[mt] = *reinterpret_cast<const bf16x8*>(w1A + (((mt << 1) + ks) << 9) + lane * 8);
      bf16x8 bf[2];
      #pragma unroll
      for (int nt = 0; nt < 2; ++nt)
        bf[nt] = lds_frag(H + (s0 + nt * 16 + m) * 136 + ks * 32 + q * 8);
      #pragma unroll
      for (int mt = 0; mt < 8; ++mt)
        #pragma unroll
        for (int nt = 0; nt < 2; ++nt)
          acc[mt][nt] = mfma16(a[mt], bf[nt], acc[mt][nt]);
    }
    #pragma unroll
    for (int mt = 0; mt < 8; ++mt) {
      float4 bb = *reinterpret_cast<const float4*>(b1 + mt * 16 + q * 4);
      #pragma unroll
      for (int nt = 0; nt < 2; ++nt) {
        float v0 = fmaxf(acc[mt][nt][0] + bb.x, 0.0f);
        float v1 = fmaxf(acc[mt][nt][1] + bb.y, 0.0f);
        float v2 = fmaxf(acc[mt][nt][2] + bb.z, 0.0f);
        float v3 = fmaxf(acc[mt][nt][3] + bb.w, 0.0f);
        uint2 pk; pk.x = pk2bf(v0, v1); pk.y = pk2bf(v2, v3);
        *reinterpret_cast<uint2*>(&H[(s0 + nt * 16 + m) * 136 + mt * 16 + q * 4]) = pk;
      }
    }
  }

  // ---- layer 2: D^T = w2A(128x128) x H1(B) -> H (relu), in place ----
  {
    floatx4 acc[8][2] = {};
    #pragma unroll 1
    for (int ks = 0; ks < 4; ++ks) {
      bf16x8 a[8];
      #pragma unroll
      for (int mt = 0; mt < 8; ++mt)
        a[mt] = *reinterpret_cast<const bf16x8*>(w2A + (((mt << 2) + ks) << 9) + lane * 8);
      bf16x8 bf[2];
      #pragma unroll
      for (int nt = 0; nt < 2; ++nt)
        bf[nt] = lds_frag(H + (s0 + nt * 16 + m) * 136 + ks * 32 + q * 8);
      #pragma unroll
      for (int mt = 0; mt < 8; ++mt)
        #pragma unroll
        for (int nt = 0; nt < 2; ++nt)
          acc[mt][nt] = mfma16(a[mt], bf[nt], acc[mt][nt]);
    }
    #pragma unroll
    for (int mt = 0; mt < 8; ++mt) {
      float4 bb = *reinterpret_cast<const float4*>(b2 + mt * 16 + q * 4);
      #pragma unroll
      for (int nt = 0; nt < 2; ++nt) {
        float v0 = fmaxf(acc[mt][nt][0] + bb.x, 0.0f);
        float v1 = fmaxf(acc[mt][nt][1] + bb.y, 0.0f);
        float v2 = fmaxf(acc[mt][nt][2] + bb.z, 0.0f);
        float v3 = fmaxf(acc[mt][nt][3] + bb.w, 0.0f);
        uint2 pk; pk.x = pk2bf(v0, v1); pk.y = pk2bf(v2, v3);
        *reinterpret_cast<uint2*>(&H[(s0 + nt * 16 + m) * 136 + mt * 16 + q * 4]) = pk;
      }
    }
  }

  // ---- layer 3: D^T = w3A(32x128) x H2(B) (+dcon direct), mask, NHWC ----
  {
    floatx4 acc[2][2];
    const float* dg = dconG + (size_t)blockIdx.x * 512;
    #pragma unroll
    for (int nt = 0; nt < 2; ++nt) {
      int s = s0 + nt * 16 + m;
      #pragma unroll
      for (int mt = 0; mt < 2; ++mt)
        acc[mt][nt] = *reinterpret_cast<const floatx4*>(dg + (s >> 2) * 32 + mt * 16 + q * 4);
    }
    #pragma unroll 1
    for (int ks = 0; ks < 4; ++ks) {
      bf16x8 a[2];
      #pragma unroll
      for (int mt = 0; mt < 2; ++mt)
        a[mt] = *reinterpret_cast<const bf16x8*>(w3A + (((mt << 2) + ks) << 9) + lane * 8);
      bf16x8 bf[2];
      #pragma unroll
      for (int nt = 0; nt < 2; ++nt)
        bf[nt] = lds_frag(H + (s0 + nt * 16 + m) * 136 + ks * 32 + q * 8);
      #pragma unroll
      for (int mt = 0; mt < 2; ++mt)
        #pragma unroll
        for (int nt = 0; nt < 2; ++nt)
          acc[mt][nt] = mfma16(a[mt], bf[nt], acc[mt][nt]);
    }
    #pragma unroll
    for (int nt = 0; nt < 2; ++nt) {
      int s = s0 + nt * 16 + m;
      float z = zbufs[blockIdx.x * 64 + s];
      float mk = (z > thresh) ? 1.0f : 0.0f;
      unsigned short* dst = rdmp + (size_t)blockIdx.x * 2048 + s * 32 + q * 4;
      #pragma unroll
      for (int mt = 0; mt < 2; ++mt) {
        uint2 pk;
        pk.x = pk2bf(acc[mt][nt][0] * mk, acc[mt][nt][1] * mk);
        pk.y = pk2bf(acc[mt][nt][2] * mk, acc[mt][nt][3] * mk);
        *reinterpret_cast<uint2*>(dst + mt * 16) = pk;
      }
    }
  }
}

// ---------------- NHWC 3x3 conv via MFMA ----------------
template<int CIN, int COUT, int WAVES, int MODE>
__global__ __launch_bounds__(WAVES * 64, 3) void conv3x3(
    const unsigned short* __restrict__ in, const unsigned short* __restrict__ wt,
    const float* __restrict__ bias, const unsigned short* __restrict__ rdmp,
    unsigned short* __restrict__ out) {
  constexpr int CP  = CIN + 8;
  constexpr int CH8 = CIN / 8;
  constexpr int KC  = CIN / 32;
  constexpr int NT  = COUT / (WAVES * 16);
  __shared__ __align__(16) unsigned short lds_in[6 * 18 * CP];

  const int tid = threadIdx.x;
  const int x0 = blockIdx.x * 16, y0 = blockIdx.y * 4;

  for (int i = tid; i < 108 * CH8; i += WAVES * 64) {
    int pix = i / CH8, part = i - pix * CH8;
    int xx = pix % 18, yy = pix / 18;
    int gx = x0 - 1 + xx, gy = y0 - 1 + yy;
    ushort8 v = {0, 0, 0, 0, 0, 0, 0, 0};
    if (gx >= 0 && gx < IMGW && gy >= 0 && gy < IMGW)
      v = *reinterpret_cast<const ushort8*>(in + ((size_t)(gy * IMGW + gx)) * CIN + part * 8);
    *reinterpret_cast<ushort8*>(&lds_in[pix * CP + part * 8]) = v;
  }
  __syncthreads();

  const int wave = tid >> 6, lane = tid & 63, q = lane >> 4, m = lane & 15;
  floatx4 acc[4][NT] = {};

  #pragma unroll 1
  for (int kc = 0; kc < KC; ++kc) {
    bf16x8 a[6][3];
    #pragma unroll
    for (int rr = 0; rr < 6; ++rr)
      #pragma unroll
      for (int dx = 0; dx < 3; ++dx)
        a[rr][dx] = lds_frag(&lds_in[(rr * 18 + m + dx) * CP + kc * 32 + q * 8]);
    #pragma unroll
    for (int nb = 0; nb < 9; ++nb) {
      int dy = nb / 3, dx = nb - dy * 3;
      int ks = nb * KC + kc;
      #pragma unroll
      for (int nt = 0; nt < NT; ++nt) {
        bf16x8 b = *reinterpret_cast<const bf16x8*>(
            wt + ((((size_t)ks * WAVES + wave) * NT + nt) << 9) + lane * 8);
        #pragma unroll
        for (int mt = 0; mt < 4; ++mt)
          acc[mt][nt] = mfma16(a[mt + dy][dx], b, acc[mt][nt]);
      }
    }
  }

  const int co0 = wave * (COUT / WAVES);
  #pragma unroll
  for (int mt = 0; mt < 4; ++mt) {
    int y = y0 + mt;
    #pragma unroll
    for (int nt = 0; nt < NT; ++nt) {
      int co = co0 + nt * 16 + m;
      float bb = bias[co];
      #pragma unroll
      for (int r = 0; r < 4; ++r) {
        int pixel = y * IMGW + x0 + q * 4 + r;
        float v = acc[mt][nt][r] + bb;
        if (MODE == 0) {
          v = fmaxf(v, 0.0f);
        } else {
          v = 1.0f / (1.0f + __expf(-v));
          v *= bf2f(rdmp[(size_t)pixel * 128 + co]);
        }
        out[(size_t)pixel * COUT + co] = f2bf(v);
      }
    }
  }
}

// ---------------- final 64->3 conv + sigmoid, fp32 NHWC out ----------------
__global__ __launch_bounds__(256) void uconv3_kernel(
    const unsigned short* __restrict__ u2, const float* __restrict__ w,
    const float* __restrict__ b, float* __restrict__ out) {
  __shared__ float wl[1728];   // [nb][ci][c]
  for (int i = threadIdx.x; i < 1728; i += 256) {
    int c = i % 3; int t = i / 3; int ci = t & 63; int nb = t >> 6;
    wl[i] = w[(c * 64 + ci) * 9 + nb];
  }
  __syncthreads();
  int pixel = blockIdx.x * 256 + threadIdx.x;
  int py = pixel / IMGW, px = pixel - py * IMGW;
  float a0 = b[0], a1 = b[1], a2 = b[2];
  for (int nb = 0; nb < 9; ++nb) {
    int gy = py + nb / 3 - 1, gx = px + nb % 3 - 1;
    if (gx < 0 || gx >= IMGW || gy < 0 || gy >= IMGW) continue;
    const unsigned short* src = u2 + (size_t)(gy * IMGW + gx) * 64;
    const float* wp = wl + nb * 192;
    #pragma unroll
    for (int cc = 0; cc < 8; ++cc) {
      ushort8 v = *reinterpret_cast<const ushort8*>(src + cc * 8);
      #pragma unroll
      for (int j = 0; j < 8; ++j) {
        float uv = bf2f(v[j]);
        const float* w3p = wp + (cc * 8 + j) * 3;
        a0 += uv * w3p[0]; a1 += uv * w3p[1]; a2 += uv * w3p[2];
      }
    }
  }
  float* o = out + (size_t)pixel * 3;
  o[0] = 1.0f / (1.0f + __expf(-a0));
  o[1] = 1.0f / (1.0f + __expf(-a1));
  o[2] = 1.0f / (1.0f + __expf(-a2));
}

extern "C" void kernel_launch(void* const* d_in, const int* in_sizes, int n_in,
                              void* d_out, int out_size, void* d_ws, size_t ws_size,
                              hipStream_t stream) {
  (void)in_sizes; (void)n_in; (void)out_size; (void)ws_size;
  const float* zbufs = (const float*)d_in[0];
  const float* ray   = (const float*)d_in[1];
  const int* isTrain = (const int*)d_in[4];
  const float* w1 = (const float*)d_in[6];
  const float* b1 = (const float*)d_in[7];
  const float* w2 = (const float*)d_in[8];
  const float* b2 = (const float*)d_in[9];
  const float* w3 = (const float*)d_in[10];
  const float* b3 = (const float*)d_in[11];
  const float* mpn_w1 = (const float*)d_in[12];
  const float* mpn_b1 = (const float*)d_in[13];
  const float* mpn_w2 = (const float*)d_in[14];
  const float* mpn_b2 = (const float*)d_in[15];
  const float* uw1 = (const float*)d_in[16];
  const float* ub1 = (const float*)d_in[17];
  const float* uw2 = (const float*)d_in[18];
  const float* ub2 = (const float*)d_in[19];
  const float* uw3 = (const float*)d_in[20];
  const float* ub3 = (const float*)d_in[21];
  float* out = (float*)d_out;

  unsigned char* ws = (unsigned char*)d_ws;
  size_t off = 0;
  auto alloc = [&](size_t bytes) -> void* {
    void* p = ws + off; off = (off + bytes + 255) & ~(size_t)255; return p;
  };
  unsigned short* w1A  = (unsigned short*)alloc(8192 * 2);
  unsigned short* w2A  = (unsigned short*)alloc(16384 * 2);
  unsigned short* w3A  = (unsigned short*)alloc(4096 * 2);
  unsigned short* cw1  = (unsigned short*)alloc((size_t)128 * 1152 * 2);
  unsigned short* cw2  = (unsigned short*)alloc((size_t)128 * 1152 * 2);
  unsigned short* cu1  = (unsigned short*)alloc((size_t)64 * 1152 * 2);
  unsigned short* cu2  = (unsigned short*)alloc((size_t)64 * 576 * 2);
  unsigned short* rdmp = (unsigned short*)alloc((size_t)NPIX * 128 * 2);
  unsigned short* t1   = (unsigned short*)alloc((size_t)NPIX * 128 * 2);
  unsigned short* fuse = (unsigned short*)alloc((size_t)NPIX * 128 * 2);
  unsigned short* u1 = t1;            // t1 dead after conv2
  unsigned short* u2 = rdmp;          // rdmp dead after conv2 (fuse epilogue)
  float* dconG = (float*)fuse;        // dconG dead before conv2 writes fuse

  prep_mlpA<<<112, 256, 0, stream>>>(w1, w2, w3, w1A, w2A, w3A);
  prep_convB<<<576, 256, 0, stream>>>(mpn_w1, cw1, 128 * 1152, 128, 4, 2);
  prep_convB<<<576, 256, 0, stream>>>(mpn_w2, cw2, 128 * 1152, 128, 4, 2);
  prep_convB<<<288, 256, 0, stream>>>(uw1, cu1, 64 * 1152, 128, 2, 2);
  prep_convB<<<144, 256, 0, stream>>>(uw2, cu2, 64 * 576, 64, 2, 2);

  dcon_kernel<<<NPIX * 32 / 256, 256, 0, stream>>>(ray, w3, b3, dconG);
  mlp_kernel<<<NPIX * 4 / 64, 128, 0, stream>>>(zbufs, ray, isTrain, b1, b2,
                                                w1A, w2A, w3A, dconG, rdmp);

  dim3 cgrid(IMGW / 16, IMGW / 4);
  conv3x3<128, 128, 4, 0><<<cgrid, 256, 0, stream>>>(rdmp, cw1, mpn_b1, nullptr, t1);
  conv3x3<128, 128, 4, 1><<<cgrid, 256, 0, stream>>>(t1, cw2, mpn_b2, rdmp, fuse);
  conv3x3<128, 64, 2, 0><<<cgrid, 128, 0, stream>>>(fuse, cu1, ub1, nullptr, u1);
  conv3x3<64, 64, 2, 0><<<cgrid, 128, 0, stream>>>(u1, cu2, ub2, nullptr, u2);
  uconv3_kernel<<<NPIX / 256, 256, 0, stream>>>(u2, uw3, ub3, out);
}